// Round 6
// baseline (87.089 us; speedup 1.0000x reference)
//
#include <hip/hip_runtime.h>
#include <hip/hip_bf16.h>

#define B_    4
#define C_    256
#define H_    180
#define W_    180
#define NBOX  64
#define HW_   (H_ * W_)
#define TILES ((HW_ + 255) / 256)   // 127 tiles of 256 pixels per image

// Grid: (TILES, B_). Block: 256 threads = 4 waves.
//   lane  -> 4 consecutive pixels (float4 loads: 16B/lane, 1KB/wave-load)
//   wave  -> 64-channel chunk
// Phase 1: each thread accumulates 0.5*(x-t)^2 and any(t!=0) per pixel over
// its wave's channels (float4 over pixels). Phase 2: combine the 4 waves'
// per-pixel partials in LDS, gate by (box mask & anynz), reduce, atomics.
__global__ __launch_bounds__(256) void mask_feat_loss_main(
    const float* __restrict__ x,
    const float* __restrict__ t,
    const int*   __restrict__ boxes,
    float*        ws_sum,
    unsigned int* ws_cnt)
{
    const int lane = threadIdx.x & 63;
    const int wid  = threadIdx.x >> 6;
    const int tile = blockIdx.x;
    const int b    = blockIdx.y;
    const int hw0  = tile * 256 + lane * 4;      // first of this lane's 4 pixels

    __shared__ int           sbox[NBOX * 4];     // 1 KB
    __shared__ float         ssum[4][256];       // 4 KB
    __shared__ unsigned char snz[4][256];        // 1 KB
    __shared__ unsigned char smask[256];         // 256 B

    // Cooperative box stage (b is block-uniform): 256 ints, one per thread.
    sbox[threadIdx.x] = boxes[b * NBOX * 4 + threadIdx.x];
    __syncthreads();

    const bool active = (hw0 + 3) < HW_;         // tail tile: lanes >= 36 idle

    // Per-pixel box mask from LDS.
    int m0 = 0, m1 = 0, m2 = 0, m3 = 0;
    if (active) {
        int hh[4], ww[4];
        #pragma unroll
        for (int k = 0; k < 4; ++k) { hh[k] = (hw0 + k) / W_; ww[k] = (hw0 + k) % W_; }
        #pragma unroll 8
        for (int n = 0; n < NBOX; ++n) {
            const int ltx = sbox[n * 4 + 0];
            const int lty = sbox[n * 4 + 1];
            const int rbx = sbox[n * 4 + 2];
            const int rby = sbox[n * 4 + 3];
            m0 |= ((hh[0] >= lty) & (hh[0] < rby) & (ww[0] >= rbx) & (ww[0] < ltx));
            m1 |= ((hh[1] >= lty) & (hh[1] < rby) & (ww[1] >= rbx) & (ww[1] < ltx));
            m2 |= ((hh[2] >= lty) & (hh[2] < rby) & (ww[2] >= rbx) & (ww[2] < ltx));
            m3 |= ((hh[3] >= lty) & (hh[3] < rby) & (ww[3] >= rbx) & (ww[3] < ltx));
        }
    }

    float a0 = 0.f, a1 = 0.f, a2 = 0.f, a3 = 0.f;
    int   n0 = 0, n1 = 0, n2 = 0, n3 = 0;

    if (active && (m0 | m1 | m2 | m3)) {
        const size_t base = ((size_t)(b * C_ + wid * 64)) * HW_ + hw0;
        const float4* xp = (const float4*)(x + base);
        const float4* tp = (const float4*)(t + base);
        const size_t cstride = HW_ / 4;          // 8100 float4s per channel
        #pragma unroll 4
        for (int c = 0; c < 64; ++c) {
            const float4 tv = tp[(size_t)c * cstride];
            const float4 xv = xp[(size_t)c * cstride];
            n0 |= (tv.x != 0.0f); n1 |= (tv.y != 0.0f);
            n2 |= (tv.z != 0.0f); n3 |= (tv.w != 0.0f);
            float d0 = xv.x - tv.x, d1 = xv.y - tv.y;
            float d2 = xv.z - tv.z, d3 = xv.w - tv.w;
            float t0 = 0.5f * d0 * d0, t1 = 0.5f * d1 * d1;
            float t2 = 0.5f * d2 * d2, t3 = 0.5f * d3 * d3;
            if (isnan(tv.x)) t0 = 0.f;  if (isnan(tv.y)) t1 = 0.f;
            if (isnan(tv.z)) t2 = 0.f;  if (isnan(tv.w)) t3 = 0.f;
            a0 += t0; a1 += t1; a2 += t2; a3 += t3;
        }
    }

    const int pi = lane * 4;
    ssum[wid][pi + 0] = a0; ssum[wid][pi + 1] = a1;
    ssum[wid][pi + 2] = a2; ssum[wid][pi + 3] = a3;
    snz[wid][pi + 0] = (unsigned char)n0; snz[wid][pi + 1] = (unsigned char)n1;
    snz[wid][pi + 2] = (unsigned char)n2; snz[wid][pi + 3] = (unsigned char)n3;
    if (wid == 0) {
        smask[pi + 0] = (unsigned char)m0; smask[pi + 1] = (unsigned char)m1;
        smask[pi + 2] = (unsigned char)m2; smask[pi + 3] = (unsigned char)m3;
    }
    __syncthreads();

    // Phase 2: thread tid owns pixel tid of the tile.
    const int tid = threadIdx.x;
    const int hw  = tile * 256 + tid;
    float stot = ssum[0][tid] + ssum[1][tid] + ssum[2][tid] + ssum[3][tid];
    int   nzt  = snz[0][tid] | snz[1][tid] | snz[2][tid] | snz[3][tid];
    const bool ok = (hw < HW_) && smask[tid] && nzt;
    float sc = ok ? stot : 0.0f;
    int   cc = ok ? 1 : 0;

    #pragma unroll
    for (int off = 32; off > 0; off >>= 1) {
        sc += __shfl_down(sc, off, 64);
        cc += __shfl_down(cc, off, 64);
    }
    if ((tid & 63) == 0) {
        if (sc != 0.0f) atomicAdd(ws_sum, sc);
        if (cc != 0)    atomicAdd(ws_cnt, (unsigned int)cc);
    }
}

__global__ void mask_feat_loss_finalize(const float* ws_sum,
                                        const unsigned int* ws_cnt,
                                        float* out)
{
    const float S = ws_sum[0];
    const float n = (float)ws_cnt[0];
    out[0] = S / (n * (float)C_ * (float)B_);
}

extern "C" void kernel_launch(void* const* d_in, const int* in_sizes, int n_in,
                              void* d_out, int out_size, void* d_ws, size_t ws_size,
                              hipStream_t stream)
{
    const float* x     = (const float*)d_in[0];
    const float* t     = (const float*)d_in[1];
    const int*   boxes = (const int*)d_in[2];
    float* out = (float*)d_out;

    float*        ws_sum = (float*)d_ws;
    unsigned int* ws_cnt = (unsigned int*)((char*)d_ws + sizeof(float));

    hipMemsetAsync(d_ws, 0, 2 * sizeof(unsigned int), stream);

    dim3 grid(TILES, B_);
    mask_feat_loss_main<<<grid, 256, 0, stream>>>(x, t, boxes, ws_sum, ws_cnt);
    mask_feat_loss_finalize<<<1, 1, 0, stream>>>(ws_sum, ws_cnt, out);
}

// Round 7
// 81.048 us; speedup vs baseline: 1.0745x; 1.0745x over previous
//
#include <hip/hip_runtime.h>
#include <hip/hip_bf16.h>

#define B_    4
#define C_    256
#define H_    180
#define W_    180
#define NBOX  64
#define HW_   (H_ * W_)
#define TILES ((HW_ + 255) / 256)   // 127 tiles of 256 pixels per image

// Grid: (TILES, B_). Block: 256 threads = 4 waves.
//   lane -> 4 consecutive pixels (float4); wave -> 64-channel chunk.
// Channel loop is hand-pipelined: two ping-pong batches of 8 channels,
// 16 float4 loads issued into named registers before the previous batch is
// consumed -> ~16 KB in flight per wave (forces MLP the compiler refused to
// create on its own; round-6 evidence: VGPR_Count=24 == serialized loads).
__global__ __launch_bounds__(256) void mask_feat_loss_main(
    const float* __restrict__ x,
    const float* __restrict__ t,
    const int*   __restrict__ boxes,
    float*        ws_sum,
    unsigned int* ws_cnt)
{
    const int tid  = threadIdx.x;
    const int lane = tid & 63;
    const int wid  = tid >> 6;
    const int tile = blockIdx.x;
    const int b    = blockIdx.y;
    const int hw0  = tile * 256 + lane * 4;

    __shared__ int           sbox[NBOX * 4];
    __shared__ float         ssum[4][256];
    __shared__ unsigned char snz[4][256];
    __shared__ unsigned char smask[256];

    sbox[tid] = boxes[b * NBOX * 4 + tid];
    __syncthreads();

    const bool active = (hw0 + 3) < HW_;     // tail tile: lanes >= 36 idle

    int m0 = 0, m1 = 0, m2 = 0, m3 = 0;
    if (active) {
        int hh[4], ww[4];
        #pragma unroll
        for (int k = 0; k < 4; ++k) { hh[k] = (hw0 + k) / W_; ww[k] = (hw0 + k) % W_; }
        #pragma unroll 8
        for (int n = 0; n < NBOX; ++n) {
            const int ltx = sbox[n * 4 + 0];
            const int lty = sbox[n * 4 + 1];
            const int rbx = sbox[n * 4 + 2];
            const int rby = sbox[n * 4 + 3];
            m0 |= ((hh[0] >= lty) & (hh[0] < rby) & (ww[0] >= rbx) & (ww[0] < ltx));
            m1 |= ((hh[1] >= lty) & (hh[1] < rby) & (ww[1] >= rbx) & (ww[1] < ltx));
            m2 |= ((hh[2] >= lty) & (hh[2] < rby) & (ww[2] >= rbx) & (ww[2] < ltx));
            m3 |= ((hh[3] >= lty) & (hh[3] < rby) & (ww[3] >= rbx) & (ww[3] < ltx));
        }
    }

    float a0 = 0.f, a1 = 0.f, a2 = 0.f, a3 = 0.f;
    int   n0 = 0, n1 = 0, n2 = 0, n3 = 0;

    if (active && (m0 | m1 | m2 | m3)) {
        const size_t base = ((size_t)(b * C_ + wid * 64)) * HW_ + hw0;
        const float4* xp = (const float4*)(x + base);
        const float4* tp = (const float4*)(t + base);
        const size_t cs = HW_ / 4;           // 8100 float4 per channel plane

        float4 tA[8], xA[8], tB[8], xB[8];

        #define LOADB(TT, XX, CBASE)                                   \
            _Pragma("unroll")                                          \
            for (int k = 0; k < 8; ++k) {                              \
                TT[k] = tp[(size_t)((CBASE) + k) * cs];                \
                XX[k] = xp[(size_t)((CBASE) + k) * cs];                \
            }

        #define CONSUME(TT, XX)                                        \
            _Pragma("unroll")                                          \
            for (int k = 0; k < 8; ++k) {                              \
                const float4 tv = TT[k];                               \
                const float4 xv = XX[k];                               \
                n0 |= (tv.x != 0.f); n1 |= (tv.y != 0.f);              \
                n2 |= (tv.z != 0.f); n3 |= (tv.w != 0.f);              \
                float d0 = xv.x - tv.x, d1 = xv.y - tv.y;              \
                float d2 = xv.z - tv.z, d3 = xv.w - tv.w;              \
                float s0 = 0.5f * d0 * d0, s1 = 0.5f * d1 * d1;        \
                float s2 = 0.5f * d2 * d2, s3 = 0.5f * d3 * d3;        \
                if (isnan(tv.x)) s0 = 0.f; if (isnan(tv.y)) s1 = 0.f;  \
                if (isnan(tv.z)) s2 = 0.f; if (isnan(tv.w)) s3 = 0.f;  \
                a0 += s0; a1 += s1; a2 += s2; a3 += s3;                \
            }

        LOADB(tA, xA, 0)
        #pragma unroll
        for (int cb = 0; cb < 64; cb += 16) {
            LOADB(tB, xB, cb + 8)            // B in flight while A consumed
            CONSUME(tA, xA)
            if (cb + 16 < 64) {
                LOADB(tA, xA, cb + 16)       // A in flight while B consumed
            }
            CONSUME(tB, xB)
        }
        #undef LOADB
        #undef CONSUME
    }

    const int pi = lane * 4;
    ssum[wid][pi + 0] = a0; ssum[wid][pi + 1] = a1;
    ssum[wid][pi + 2] = a2; ssum[wid][pi + 3] = a3;
    snz[wid][pi + 0] = (unsigned char)n0; snz[wid][pi + 1] = (unsigned char)n1;
    snz[wid][pi + 2] = (unsigned char)n2; snz[wid][pi + 3] = (unsigned char)n3;
    if (wid == 0) {
        smask[pi + 0] = (unsigned char)m0; smask[pi + 1] = (unsigned char)m1;
        smask[pi + 2] = (unsigned char)m2; smask[pi + 3] = (unsigned char)m3;
    }
    __syncthreads();

    // Phase 2: thread tid owns pixel tid of the tile.
    const int hw = tile * 256 + tid;
    float stot = ssum[0][tid] + ssum[1][tid] + ssum[2][tid] + ssum[3][tid];
    int   nzt  = snz[0][tid] | snz[1][tid] | snz[2][tid] | snz[3][tid];
    const bool ok = (hw < HW_) && smask[tid] && nzt;
    float sc = ok ? stot : 0.0f;
    int   cc = ok ? 1 : 0;

    #pragma unroll
    for (int off = 32; off > 0; off >>= 1) {
        sc += __shfl_down(sc, off, 64);
        cc += __shfl_down(cc, off, 64);
    }
    if ((tid & 63) == 0) {
        if (sc != 0.0f) atomicAdd(ws_sum, sc);
        if (cc != 0)    atomicAdd(ws_cnt, (unsigned int)cc);
    }
}

__global__ void mask_feat_loss_finalize(const float* ws_sum,
                                        const unsigned int* ws_cnt,
                                        float* out)
{
    const float S = ws_sum[0];
    const float n = (float)ws_cnt[0];
    out[0] = S / (n * (float)C_ * (float)B_);
}

extern "C" void kernel_launch(void* const* d_in, const int* in_sizes, int n_in,
                              void* d_out, int out_size, void* d_ws, size_t ws_size,
                              hipStream_t stream)
{
    const float* x     = (const float*)d_in[0];
    const float* t     = (const float*)d_in[1];
    const int*   boxes = (const int*)d_in[2];
    float* out = (float*)d_out;

    float*        ws_sum = (float*)d_ws;
    unsigned int* ws_cnt = (unsigned int*)((char*)d_ws + sizeof(float));

    hipMemsetAsync(d_ws, 0, 2 * sizeof(unsigned int), stream);

    dim3 grid(TILES, B_);
    mask_feat_loss_main<<<grid, 256, 0, stream>>>(x, t, boxes, ws_sum, ws_cnt);
    mask_feat_loss_finalize<<<1, 1, 0, stream>>>(ws_sum, ws_cnt, out);
}

// Round 8
// 55.761 us; speedup vs baseline: 1.5618x; 1.4535x over previous
//
#include <hip/hip_runtime.h>
#include <hip/hip_bf16.h>

#define B_    4
#define C_    256
#define H_    180
#define W_    180
#define NBOX  64
#define HW_   (H_ * W_)            // 32400
#define TILES 127                  // ceil(HW_/256)
#define CCH   16                   // channel chunks of 16
#define NBLK  (TILES * B_)         // 508

// workspace layout (bytes)
#define WMASK_OFF   0                              // u8 [B_][HW_]
#define TILEANY_OFF (WMASK_OFF + B_ * HW_)         // u8 [NBLK]
#define PSUM_OFF    130112                         // float [CCH][B_][HW_] (16B aligned)
#define PNZ_OFF     (PSUM_OFF + CCH * B_ * HW_ * 4)   // u8 [CCH][B_][HW_]
#define BSUM_OFF    (PNZ_OFF + CCH * B_ * HW_)        // float [NBLK]
#define BCNT_OFF    (BSUM_OFF + NBLK * 4)             // u32 [NBLK]
#define WS_NEED     (BCNT_OFF + NBLK * 4)             // ~10.5 MB

// ---------- Kernel M: box mask per pixel + per-tile any-mask flag ----------
__global__ __launch_bounds__(256) void mfl_mask(
    const int* __restrict__ boxes,
    unsigned char* __restrict__ wmask,
    unsigned char* __restrict__ tileany)
{
    const int tid = threadIdx.x;
    const int bx  = blockIdx.x;     // tile
    const int b   = blockIdx.y;     // batch

    __shared__ int sbox[NBOX * 4];
    __shared__ int sany;
    sbox[tid] = boxes[b * NBOX * 4 + tid];
    if (tid == 0) sany = 0;
    __syncthreads();

    const int hw = bx * 256 + tid;
    int msk = 0;
    if (hw < HW_) {
        const int h = hw / W_, w = hw - (hw / W_) * W_;
        #pragma unroll 8
        for (int n = 0; n < NBOX; ++n) {
            const int ltx = sbox[n * 4 + 0];
            const int lty = sbox[n * 4 + 1];
            const int rbx = sbox[n * 4 + 2];
            const int rby = sbox[n * 4 + 3];
            msk |= ((h >= lty) & (h < rby) & (w >= rbx) & (w < ltx));
        }
        wmask[b * HW_ + hw] = (unsigned char)msk;
    }
    if (msk) sany = 1;              // benign same-value race
    __syncthreads();
    if (tid == 0) tileany[b * TILES + bx] = (unsigned char)sany;
}

// ---------- Kernel A (hot): pure streaming partial sums ----------
// Grid (TILES, CCH, B_). Block 256 = 4 waves. Wave w covers channels
// chunk*16 + w*4 .. +3 over the tile's 256 pixels (lane -> 4 px float4).
// 8 independent 1KB loads per wave, pinned before consumption.
__global__ __launch_bounds__(256) void mfl_stream(
    const float* __restrict__ x,
    const float* __restrict__ t,
    const unsigned char* __restrict__ tileany,
    float* __restrict__ psum,
    unsigned char* __restrict__ pnz)
{
    const int tid  = threadIdx.x;
    const int lane = tid & 63;
    const int wid  = tid >> 6;
    const int bx   = blockIdx.x;    // tile
    const int k    = blockIdx.y;    // channel chunk
    const int b    = blockIdx.z;    // batch

    if (tileany[b * TILES + bx] == 0) return;   // no masked pixel in tile

    __shared__ float         ssum[4][256];
    __shared__ unsigned char snz[4][256];

    float a0 = 0.f, a1 = 0.f, a2 = 0.f, a3 = 0.f;
    int   n0 = 0, n1 = 0, n2 = 0, n3 = 0;

    const int hw0 = bx * 256 + 4 * lane;
    if (hw0 < HW_) {                // HW_ % 4 == 0 -> whole float4 valid
        const int c0 = k * 16 + wid * 4;
        const size_t base = ((size_t)(b * C_ + c0)) * HW_ + hw0;
        const float4* xp = (const float4*)(x + base);
        const float4* tp = (const float4*)(t + base);
        const size_t cs = HW_ / 4;  // 8100 float4 per channel plane

        // Issue all 8 loads (8KB/wave in flight), then consume.
        const float4 tv0 = tp[0];
        const float4 tv1 = tp[cs];
        const float4 tv2 = tp[2 * cs];
        const float4 tv3 = tp[3 * cs];
        const float4 xv0 = xp[0];
        const float4 xv1 = xp[cs];
        const float4 xv2 = xp[2 * cs];
        const float4 xv3 = xp[3 * cs];
        __builtin_amdgcn_sched_barrier(0);

        #define CONSUME(tv, xv)                                        \
        {                                                              \
            n0 += (tv.x != 0.f); n1 += (tv.y != 0.f);                  \
            n2 += (tv.z != 0.f); n3 += (tv.w != 0.f);                  \
            float d0 = xv.x - tv.x, d1 = xv.y - tv.y;                  \
            float d2 = xv.z - tv.z, d3 = xv.w - tv.w;                  \
            float s0 = 0.5f * d0 * d0, s1 = 0.5f * d1 * d1;            \
            float s2 = 0.5f * d2 * d2, s3 = 0.5f * d3 * d3;            \
            if (isnan(tv.x)) s0 = 0.f;  if (isnan(tv.y)) s1 = 0.f;     \
            if (isnan(tv.z)) s2 = 0.f;  if (isnan(tv.w)) s3 = 0.f;     \
            a0 += s0; a1 += s1; a2 += s2; a3 += s3;                    \
        }
        CONSUME(tv0, xv0)
        CONSUME(tv1, xv1)
        CONSUME(tv2, xv2)
        CONSUME(tv3, xv3)
        #undef CONSUME
    }

    const int pi = 4 * lane;
    ssum[wid][pi + 0] = a0; ssum[wid][pi + 1] = a1;
    ssum[wid][pi + 2] = a2; ssum[wid][pi + 3] = a3;
    snz[wid][pi + 0] = (unsigned char)n0; snz[wid][pi + 1] = (unsigned char)n1;
    snz[wid][pi + 2] = (unsigned char)n2; snz[wid][pi + 3] = (unsigned char)n3;
    __syncthreads();

    const int hw = bx * 256 + tid;
    if (hw < HW_) {
        const float tot = ssum[0][tid] + ssum[1][tid] + ssum[2][tid] + ssum[3][tid];
        const int   nzc = snz[0][tid] + snz[1][tid] + snz[2][tid] + snz[3][tid];
        const size_t plane = (size_t)(k * B_ + b) * HW_;
        psum[plane + hw] = tot;
        pnz[plane + hw]  = (unsigned char)nzc;
    }
}

// ---------- Kernel B: gate by mask & anynz, per-block partials ----------
__global__ __launch_bounds__(256) void mfl_gate(
    const float* __restrict__ psum,
    const unsigned char* __restrict__ pnz,
    const unsigned char* __restrict__ wmask,
    float* __restrict__ bsum,
    unsigned int* __restrict__ bcnt)
{
    const int tid = threadIdx.x;
    const int bx  = blockIdx.x;
    const int b   = blockIdx.y;
    const int hw  = bx * 256 + tid;

    float s = 0.f;
    int   nz = 0;
    int   msk = 0;
    if (hw < HW_) {
        msk = wmask[b * HW_ + hw];
        if (msk) {
            #pragma unroll
            for (int k = 0; k < CCH; ++k) {
                const size_t idx = (size_t)(k * B_ + b) * HW_ + hw;
                s  += psum[idx];
                nz += pnz[idx];
            }
        }
    }
    const bool ok = msk && (nz > 0);
    float sc = ok ? s : 0.f;
    int   cc = ok ? 1 : 0;

    #pragma unroll
    for (int off = 32; off > 0; off >>= 1) {
        sc += __shfl_down(sc, off, 64);
        cc += __shfl_down(cc, off, 64);
    }
    __shared__ float ws[4];
    __shared__ int   wc[4];
    if ((tid & 63) == 0) { ws[tid >> 6] = sc; wc[tid >> 6] = cc; }
    __syncthreads();
    if (tid == 0) {
        bsum[b * TILES + bx] = ws[0] + ws[1] + ws[2] + ws[3];
        bcnt[b * TILES + bx] = (unsigned int)(wc[0] + wc[1] + wc[2] + wc[3]);
    }
}

// ---------- Kernel C: final scalar ----------
__global__ __launch_bounds__(512) void mfl_final(
    const float* __restrict__ bsum,
    const unsigned int* __restrict__ bcnt,
    float* __restrict__ out)
{
    const int tid = threadIdx.x;
    float s = (tid < NBLK) ? bsum[tid] : 0.f;
    int   c = (tid < NBLK) ? (int)bcnt[tid] : 0;
    #pragma unroll
    for (int off = 32; off > 0; off >>= 1) {
        s += __shfl_down(s, off, 64);
        c += __shfl_down(c, off, 64);
    }
    __shared__ float ws[8];
    __shared__ int   wc[8];
    if ((tid & 63) == 0) { ws[tid >> 6] = s; wc[tid >> 6] = c; }
    __syncthreads();
    if (tid == 0) {
        float S = 0.f; int n = 0;
        #pragma unroll
        for (int i = 0; i < 8; ++i) { S += ws[i]; n += wc[i]; }
        out[0] = S / ((float)n * (float)C_ * (float)B_);
    }
}

// ---------- Fallback (ws too small): round-4 fused kernel ----------
__global__ __launch_bounds__(256) void mfl_fallback(
    const float* __restrict__ x, const float* __restrict__ t,
    const int* __restrict__ boxes, float* ws_sum, unsigned int* ws_cnt)
{
    const int p = blockIdx.x * blockDim.x + threadIdx.x;
    float s = 0.0f; int cnt = 0;
    if (p < B_ * HW_) {
        const int b = p / HW_, hw = p - b * HW_;
        const int h = hw / W_, w = hw - h * W_;
        bool mask = false;
        const int* bb = boxes + b * NBOX * 4;
        for (int n = 0; n < NBOX; ++n) {
            mask |= ((h >= bb[n*4+1]) & (h < bb[n*4+3]) & (w >= bb[n*4+2]) & (w < bb[n*4+0]));
        }
        if (mask) {
            const float* xp = x + (size_t)b * C_ * HW_ + hw;
            const float* tp = t + (size_t)b * C_ * HW_ + hw;
            bool anynz = false;
            for (int c = 0; c < C_; ++c) {
                const float tv = tp[(size_t)c * HW_], xv = xp[(size_t)c * HW_];
                anynz |= (tv != 0.0f);
                const float d = xv - tv;
                float term = 0.5f * d * d;
                if (isnan(tv)) term = 0.0f;
                s += term;
            }
            if (anynz) cnt = 1; else s = 0.0f;
        }
    }
    for (int off = 32; off > 0; off >>= 1) {
        s += __shfl_down(s, off, 64); cnt += __shfl_down(cnt, off, 64);
    }
    __shared__ float ssum[4]; __shared__ int scnt[4];
    if ((threadIdx.x & 63) == 0) { ssum[threadIdx.x >> 6] = s; scnt[threadIdx.x >> 6] = cnt; }
    __syncthreads();
    if (threadIdx.x == 0) {
        const float S = ssum[0]+ssum[1]+ssum[2]+ssum[3];
        const int Cn = scnt[0]+scnt[1]+scnt[2]+scnt[3];
        if (S != 0.0f) atomicAdd(ws_sum, S);
        if (Cn != 0) atomicAdd(ws_cnt, (unsigned int)Cn);
    }
}

__global__ void mfl_fallback_final(const float* ws_sum, const unsigned int* ws_cnt, float* out)
{
    out[0] = ws_sum[0] / ((float)ws_cnt[0] * (float)C_ * (float)B_);
}

extern "C" void kernel_launch(void* const* d_in, const int* in_sizes, int n_in,
                              void* d_out, int out_size, void* d_ws, size_t ws_size,
                              hipStream_t stream)
{
    const float* x     = (const float*)d_in[0];
    const float* t     = (const float*)d_in[1];
    const int*   boxes = (const int*)d_in[2];
    float* out = (float*)d_out;
    char* ws = (char*)d_ws;

    if (ws_size < (size_t)WS_NEED) {
        // Fallback: round-4 path (needs only 8 bytes of ws).
        float* ws_sum = (float*)ws;
        unsigned int* ws_cnt = (unsigned int*)(ws + 4);
        hipMemsetAsync(d_ws, 0, 8, stream);
        mfl_fallback<<<(B_ * HW_ + 255) / 256, 256, 0, stream>>>(x, t, boxes, ws_sum, ws_cnt);
        mfl_fallback_final<<<1, 1, 0, stream>>>(ws_sum, ws_cnt, out);
        return;
    }

    unsigned char* wmask   = (unsigned char*)(ws + WMASK_OFF);
    unsigned char* tileany = (unsigned char*)(ws + TILEANY_OFF);
    float*         psum    = (float*)(ws + PSUM_OFF);
    unsigned char* pnz     = (unsigned char*)(ws + PNZ_OFF);
    float*         bsum    = (float*)(ws + BSUM_OFF);
    unsigned int*  bcnt    = (unsigned int*)(ws + BCNT_OFF);

    dim3 gm(TILES, B_);
    mfl_mask<<<gm, 256, 0, stream>>>(boxes, wmask, tileany);

    dim3 ga(TILES, CCH, B_);
    mfl_stream<<<ga, 256, 0, stream>>>(x, t, tileany, psum, pnz);

    dim3 gb(TILES, B_);
    mfl_gate<<<gb, 256, 0, stream>>>(psum, pnz, wmask, bsum, bcnt);

    mfl_final<<<1, 512, 0, stream>>>(bsum, bcnt, out);
}